// Round 12
// baseline (383.044 us; speedup 1.0000x reference)
//
#include <hip/hip_runtime.h>

// SparseWeights: y = x @ (W_dense + scatter(sparse))^T + bias
// Round 12 (= round 10/11 resubmit; both failed pre-run with infra
// UnresponsiveContainer during push — no kernel signal). r8's 4-wave/
// 128x128 geometry (LDS reads 128KB/tile = 1536cy < MFMA 2484cy) + T19
// sched_group_barrier interleave so ONE wave overlaps MFMA with
// ds_read/gl_lds (AITER s02 pattern): 16 front reads, then
// 16x{MFMA4,DS_READ1}, 8x{MFMA4,VMEM1}, MFMA32. r8 failed only because
// SCHED0 fences serialized reads|MFMA within the single wave/SIMD.

typedef __attribute__((ext_vector_type(8))) __bf16 bf16x8;
typedef __attribute__((ext_vector_type(4))) float f32x4;
typedef __attribute__((ext_vector_type(8))) unsigned short u16x8;

#define BARRIER()   asm volatile("s_barrier" ::: "memory")
#define WAITVM0()   asm volatile("s_waitcnt vmcnt(0)" ::: "memory")
#define SGB(m, n)   __builtin_amdgcn_sched_group_barrier((m), (n), 0)

__device__ __forceinline__ unsigned short f2bf(float f) {
  unsigned int u = __builtin_bit_cast(unsigned int, f);
  u += 0x7FFFu + ((u >> 16) & 1u);   // round-to-nearest-even
  return (unsigned short)(u >> 16);
}

// ---- prepass 1/3: f32 -> bf16 bulk convert (vectorized x8) ----
__global__ __launch_bounds__(256) void cvt_f32_bf16(
    const float* __restrict__ s, unsigned short* __restrict__ d, long n8) {
  long i = (long)blockIdx.x * blockDim.x + threadIdx.x;
  const long stride = (long)gridDim.x * blockDim.x;
  for (; i < n8; i += stride) {
    const float4* sp = (const float4*)(s + i * 8);
    float4 a = sp[0];
    float4 b = sp[1];
    u16x8 o;
    o[0] = f2bf(a.x); o[1] = f2bf(a.y); o[2] = f2bf(a.z); o[3] = f2bf(a.w);
    o[4] = f2bf(b.x); o[5] = f2bf(b.y); o[6] = f2bf(b.z); o[7] = f2bf(b.w);
    *(u16x8*)(d + i * 8) = o;
  }
}

// ---- prepass 2/3: scatter sparse values into bf16 W ----
__global__ __launch_bounds__(256) void sparse_scatter(
    const float* __restrict__ dense, const float* __restrict__ vals,
    const int* __restrict__ rows, const int* __restrict__ cols,
    unsigned short* __restrict__ Wb, int nnz, int K) {
  int i = blockIdx.x * blockDim.x + threadIdx.x;
  if (i < nnz) {
    size_t off = (size_t)rows[i] * (size_t)K + (size_t)cols[i];
    Wb[off] = f2bf(dense[off] + vals[i]);
  }
}

// =====================================================================
// 256x256 GEMM, 256 threads = 4 waves (2Mx2N), wave tile 128x128 =
// acc[8][8] of 16x16x32 frags, BK=64 (kk=0,1). LDS 2 x (A 32K + B 32K)
// = 128 KiB dbuf -> 1 block/CU, 1 wave/SIMD. Rows 128 B = 8 quads; LDS
// quad q of row r holds global quad q^(r&7) (pre-swizzled source,
// swizzled read; 0 bank conflicts measured r6-r9).
// Per tile t (read RB, stage SB=RB^65536): issue 32 ds_reads + 8 gl_lds
// + 128 MFMAs in one region; SGB emits {16 reads; 16x[4 MFMA,1 read];
// 8x[4 MFMA,1 vmem]; 32 MFMA} -> matrix pipe busy while LDS/VMEM pipes
// drain (8 of the 16 stage VMEM ops are unnamed and fill after the
// pattern — benign; correctness rests on the vmcnt(0)+barrier fence).
// WAW: stage(t+1)->buf^1 whose readers (tile t-1) completed before the
// barrier ending t-1 < stage issue in t. Last two tiles peeled (the
// final one has no stage -> separate SGB pattern, branch-free regions).
// =====================================================================
__global__ __launch_bounds__(256, 1) void gemm4wi(
    const unsigned short* __restrict__ A,   // [Tm][K] bf16
    const unsigned short* __restrict__ B,   // [Mn][K] bf16
    const float* __restrict__ bias,
    float* __restrict__ C,
    int Tm, int Mn, int K) {
  extern __shared__ __align__(16) char smem[];   // 2 x 65536

  const int tid  = threadIdx.x;
  const int lane = tid & 63;
  const int wid  = tid >> 6;
  const int wm = (wid >> 1) * 128;
  const int wn = (wid & 1) * 128;

  // T1: XCD-aware bijective swizzle (nwg = 512, % 8 == 0)
  const int nwg = gridDim.x;
  int bid = blockIdx.x;
  if ((nwg & 7) == 0) bid = (bid & 7) * (nwg >> 3) + (bid >> 3);
  const int ntn = Mn >> 8;
  const int bm0 = (bid / ntn) << 8;
  const int bn0 = (bid % ntn) << 8;

  const int NT = K >> 6;             // K-tiles of 64 (even)

  // ---- staging maps (identical to r8, correctness-verified) ----
  const int sr  = tid >> 3;                          // 0..31
  const int gq8 = ((tid & 7) ^ (sr & 7)) * 8;        // pre-swizzled elem off
  const unsigned short* Asrc = A + (size_t)(bm0 + sr) * K + gq8;
  const unsigned short* Bsrc = B + (size_t)(bn0 + sr) * K + gq8;
  const size_t r32 = (size_t)32 * K;
  const int ldst = tid * 16;

#define STAGE8(SRC, LDSB, KOFF) do {                                             \
    _Pragma("unroll")                                                            \
    for (int c = 0; c < 8; ++c)                                                  \
      __builtin_amdgcn_global_load_lds(                                          \
        (const __attribute__((address_space(1))) void*)((SRC) + (size_t)c * r32 + (KOFF)), \
        (__attribute__((address_space(3))) void*)(smem + (LDSB) + c * 4096 + ldst), \
        16, 0, 0);                                                               \
  } while (0)

  // ---- read offsets: frag (row R, kk, cq) -> byte R*128 + ((kk*4+cq)^(R&7))*16
  const int fr = lane & 15, cq = lane >> 4;
  const int f7 = fr & 7;
  const int q0 = ((cq ^ f7) << 4);          // kk = 0
  const int q1 = (((4 + cq) ^ f7) << 4);    // kk = 1
  const int arow = (wm + fr) * 128;
  const int brow = (wn + fr) * 128;

  f32x4 acc[8][8] = {};
  bf16x8 a0[8], a1[8], b0[8], b1[8];

  // ---- prologue: stage tile 0 into buf 0 ----
  STAGE8(Asrc, 0, 0);
  STAGE8(Bsrc, 32768, 0);
  WAITVM0();
  BARRIER();

  // Tile body. RB_: read LDS base; SB_: stage base; ST_: 1 = stage t+1.
#define BODY(T_, RB_, SB_, ST_) do {                                             \
    const char* Ab = smem + (RB_);                                               \
    const char* Bb = smem + (RB_) + 32768;                                       \
    const int kn = ((T_) + 1) << 6;                                              \
    _Pragma("unroll")                                                            \
    for (int m = 0; m < 8; ++m)                                                  \
      a0[m] = *(const bf16x8*)(Ab + arow + m * 2048 + q0);                       \
    _Pragma("unroll")                                                            \
    for (int n = 0; n < 8; ++n)                                                  \
      b0[n] = *(const bf16x8*)(Bb + brow + n * 2048 + q0);                       \
    _Pragma("unroll")                                                            \
    for (int m = 0; m < 8; ++m)                                                  \
      a1[m] = *(const bf16x8*)(Ab + arow + m * 2048 + q1);                       \
    _Pragma("unroll")                                                            \
    for (int n = 0; n < 8; ++n)                                                  \
      b1[n] = *(const bf16x8*)(Bb + brow + n * 2048 + q1);                       \
    if (ST_) { STAGE8(Asrc, (SB_), kn); STAGE8(Bsrc, (SB_) + 32768, kn); }       \
    _Pragma("unroll")                                                            \
    for (int m = 0; m < 8; ++m)                                                  \
      _Pragma("unroll")                                                          \
      for (int n = 0; n < 8; ++n)                                                \
        acc[m][n] = __builtin_amdgcn_mfma_f32_16x16x32_bf16(a0[m], b0[n], acc[m][n], 0, 0, 0); \
    _Pragma("unroll")                                                            \
    for (int m = 0; m < 8; ++m)                                                  \
      _Pragma("unroll")                                                          \
      for (int n = 0; n < 8; ++n)                                                \
        acc[m][n] = __builtin_amdgcn_mfma_f32_16x16x32_bf16(a1[m], b1[n], acc[m][n], 0, 0, 0); \
    /* T19 schedule: front 16 reads; kk0 MFMAs hide kk1 reads; kk1 MFMAs */      \
    /* hide the stages; tail MFMAs clean. */                                     \
    SGB(0x100, 16);                                                              \
    _Pragma("unroll")                                                            \
    for (int g = 0; g < 16; ++g) { SGB(0x8, 4); SGB(0x100, 1); }                 \
    if (ST_) {                                                                   \
      _Pragma("unroll")                                                          \
      for (int g = 0; g < 8; ++g) { SGB(0x8, 4); SGB(0x10, 1); }                 \
      SGB(0x8, 32);                                                              \
    } else {                                                                     \
      SGB(0x8, 64);                                                              \
    }                                                                            \
    if (ST_) { WAITVM0(); }                                                      \
    BARRIER();                                                                   \
  } while (0)

  // main loop: pairs of tiles, last two peeled (final tile has no stage)
  const int NPAIR = (NT >> 1) - 1;
  for (int j = 0; j < NPAIR; ++j) {
    const int t = 2 * j;
    BODY(t,     0,     65536, 1);
    BODY(t + 1, 65536, 0,     1);
  }
  BODY(NT - 2, 0,     65536, 1);
  BODY(NT - 1, 65536, 0,     0);
#undef BODY
#undef STAGE8

  // ---- epilogue: C/D layout col = lane&15, row = (lane>>4)*4 + q ----
  const int c4 = cq * 4;
#pragma unroll
  for (int n = 0; n < 8; ++n) {
    const int col = bn0 + wn + n * 16 + fr;
    const float bv = bias[col];
#pragma unroll
    for (int m = 0; m < 8; ++m) {
      const size_t rowb = (size_t)(bm0 + wm + m * 16 + c4);
#pragma unroll
      for (int q = 0; q < 4; ++q)
        C[(rowb + q) * (size_t)Mn + col] = acc[m][n][q] + bv;
    }
  }
}

extern "C" void kernel_launch(void* const* d_in, const int* in_sizes, int n_in,
                              void* d_out, int out_size, void* d_ws, size_t ws_size,
                              hipStream_t stream) {
  const float* x     = (const float*)d_in[0];
  const float* dw    = (const float*)d_in[1];
  const float* bias  = (const float*)d_in[2];
  const float* sv    = (const float*)d_in[3];
  const int*   rows  = (const int*)d_in[4];
  const int*   cols  = (const int*)d_in[5];
  float* out = (float*)d_out;

  const int  Mn = in_sizes[2];                       // 4096
  const long wElems = (long)in_sizes[1];             // M*K
  const int  K  = (int)(wElems / Mn);                // 4096
  const long xElems = (long)in_sizes[0];             // T*K
  const int  Tm = (int)(xElems / K);                 // 8192
  const int  nnz = in_sizes[3];

  unsigned short* Wb = (unsigned short*)d_ws;        // [M*K] bf16
  unsigned short* Xb = Wb + wElems;                  // [T*K] bf16

  cvt_f32_bf16<<<2048, 256, 0, stream>>>(dw, Wb, wElems / 8);
  sparse_scatter<<<(nnz + 255) / 256, 256, 0, stream>>>(dw, sv, rows, cols, Wb, nnz, K);
  cvt_f32_bf16<<<2048, 256, 0, stream>>>(x, Xb, xElems / 8);

  dim3 grid((Tm >> 8) * (Mn >> 8));                  // 32*16 = 512
  gemm4wi<<<grid, 256, 131072, stream>>>(Xb, Wb, bias, out, Tm, Mn, K);
}

// Round 13
// 328.188 us; speedup vs baseline: 1.1671x; 1.1671x over previous
//
#include <hip/hip_runtime.h>

// SparseWeights: y = x @ (W_dense + scatter(sparse))^T + bias
// Round 13: r7 base (best: barrier-free tile interior, 260us) with
// 32x32x16 MFMA fragments: 2x FLOP/instr at ~equal pipe occupancy
// (2495 vs 2075 TF ubench) halves the MFMA instruction count and the
// per-tile MFMA pipe window (~2243 -> ~1100cy). LDS bytes unchanged.
// r12 lesson: T19 SGB interleave on 1-wave/SIMD geometry = -28%; revert.

typedef __attribute__((ext_vector_type(8))) __bf16 bf16x8;
typedef __attribute__((ext_vector_type(16))) float f32x16;
typedef __attribute__((ext_vector_type(8))) unsigned short u16x8;

#define BARRIER()   asm volatile("s_barrier" ::: "memory")
#define WAITLGKM0() asm volatile("s_waitcnt lgkmcnt(0)" ::: "memory")
#define WAITVM0()   asm volatile("s_waitcnt vmcnt(0)" ::: "memory")
#define SCHED0()    __builtin_amdgcn_sched_barrier(0)

__device__ __forceinline__ unsigned short f2bf(float f) {
  unsigned int u = __builtin_bit_cast(unsigned int, f);
  u += 0x7FFFu + ((u >> 16) & 1u);   // round-to-nearest-even
  return (unsigned short)(u >> 16);
}

// ---- prepass 1/3: f32 -> bf16 bulk convert (vectorized x8) ----
__global__ __launch_bounds__(256) void cvt_f32_bf16(
    const float* __restrict__ s, unsigned short* __restrict__ d, long n8) {
  long i = (long)blockIdx.x * blockDim.x + threadIdx.x;
  const long stride = (long)gridDim.x * blockDim.x;
  for (; i < n8; i += stride) {
    const float4* sp = (const float4*)(s + i * 8);
    float4 a = sp[0];
    float4 b = sp[1];
    u16x8 o;
    o[0] = f2bf(a.x); o[1] = f2bf(a.y); o[2] = f2bf(a.z); o[3] = f2bf(a.w);
    o[4] = f2bf(b.x); o[5] = f2bf(b.y); o[6] = f2bf(b.z); o[7] = f2bf(b.w);
    *(u16x8*)(d + i * 8) = o;
  }
}

// ---- prepass 2/3: scatter sparse values into bf16 W ----
__global__ __launch_bounds__(256) void sparse_scatter(
    const float* __restrict__ dense, const float* __restrict__ vals,
    const int* __restrict__ rows, const int* __restrict__ cols,
    unsigned short* __restrict__ Wb, int nnz, int K) {
  int i = blockIdx.x * blockDim.x + threadIdx.x;
  if (i < nnz) {
    size_t off = (size_t)rows[i] * (size_t)K + (size_t)cols[i];
    Wb[off] = f2bf(dense[off] + vals[i]);
  }
}

// =====================================================================
// 256x256 GEMM, 512 threads = 8 waves (2Mx4N), wave tile 128x64 =
// 4m x 2n frags of 32x32, acc[4][2] f32x16, BK=64 (4 k-steps of 16).
// LDS: 2 x (A 32K + B 32K) = 128 KiB dbuf. Rows 128 B = 8 quads; LDS
// quad q of row r holds global quad q^(r&7) (pre-swizzled source,
// swizzled read; 0 bank conflicts measured r6-r9).
// Tile t (buf = t&1): stage ALL of t+1 at start (8 gl_lds); 4 unfenced
// phases ks=0..3 of {6 ds_read_b128 (a[4],b[2]) -> lgkm0 -> SCHED0 ->
// setprio1 + 8 MFMA_32x32x16 + setprio0}; then vmcnt(0) (stages ~1
// tile old -> free) + single barrier.
// Frag layouts: A/B lane l -> row l&31, k = (l>>5)*8+j (32-row extension
// of the verified 16x16 pattern); C/D col = lane&31, row = (reg&3) +
// 8*(reg>>2) + 4*(lane>>5)  [m74/m101-verified].
// =====================================================================
__global__ __launch_bounds__(512, 2) void gemm32(
    const unsigned short* __restrict__ A,   // [Tm][K] bf16
    const unsigned short* __restrict__ B,   // [Mn][K] bf16
    const float* __restrict__ bias,
    float* __restrict__ C,
    int Tm, int Mn, int K) {
  extern __shared__ __align__(16) char smem[];   // 2 x 65536

  const int tid  = threadIdx.x;
  const int lane = tid & 63;
  const int wid  = tid >> 6;
  const int wm = (wid >> 2) * 128;
  const int wn = (wid & 3) * 64;

  // T1: XCD-aware bijective swizzle (nwg = 512, % 8 == 0)
  const int nwg = gridDim.x;
  int bid = blockIdx.x;
  if ((nwg & 7) == 0) bid = (bid & 7) * (nwg >> 3) + (bid >> 3);
  const int ntn = Mn >> 8;
  const int bm0 = (bid / ntn) << 8;
  const int bn0 = (bid % ntn) << 8;

  const int NT = K >> 6;             // K-tiles of 64

  // ---- staging (identical mapping to r6/r7, correctness-verified) ----
  const int sr  = tid >> 3;                          // 0..63
  const int gq8 = ((tid & 7) ^ (sr & 7)) * 8;        // pre-swizzled elem off
  const unsigned short* Asrc = A + (size_t)(bm0 + sr) * K + gq8;
  const unsigned short* Bsrc = B + (size_t)(bn0 + sr) * K + gq8;
  const size_t r64 = (size_t)64 * K;
  const int ldst = tid * 16;

#define STAGEH(SRC, H, LDSB, KOFF) do {                                          \
    __builtin_amdgcn_global_load_lds(                                            \
      (const __attribute__((address_space(1))) void*)((SRC) + (size_t)(H)*2*r64 + (KOFF)), \
      (__attribute__((address_space(3))) void*)(smem + (LDSB) + ldst), 16, 0, 0);\
    __builtin_amdgcn_global_load_lds(                                            \
      (const __attribute__((address_space(1))) void*)((SRC) + (size_t)(H)*2*r64 + r64 + (KOFF)), \
      (__attribute__((address_space(3))) void*)(smem + (LDSB) + 8192 + ldst), 16, 0, 0); \
  } while (0)

  // ---- read offsets: row base addressing for 32-row fragments ----
  const int l31 = lane & 31;
  const int kg  = lane >> 5;          // k-group 0/1 within a frag's K=16
  const int l7  = lane & 7;           // = row&7 for swizzle
  const int arow = (wm + l31) * 128;  // frag mf adds mf*32*128
  const int brow = (wn + l31) * 128;  // frag nf adds nf*32*128

  f32x16 acc[4][2] = {};
  bf16x8 a[4], b[2];

  // ---- prologue: stage tile 0 into buf 0 ----
  STAGEH(Asrc, 0, 0, 0);
  STAGEH(Asrc, 1, 16384, 0);
  STAGEH(Bsrc, 0, 32768, 0);
  STAGEH(Bsrc, 1, 49152, 0);
  WAITVM0();
  BARRIER();

#pragma unroll 2
  for (int t = 0; t < NT; ++t) {
    const char* Ab = smem + (t & 1) * 65536;
    const char* Bb = Ab + 32768;
    const int nbase = ((t & 1) ^ 1) * 65536;
    const int kn = (t + 1) * 64;

    // ---- stage ALL of tile t+1 at tile start (max latency headroom) ----
    if (t + 1 < NT) {
      STAGEH(Asrc, 0, nbase, kn);
      STAGEH(Asrc, 1, nbase + 16384, kn);
      STAGEH(Bsrc, 0, nbase + 32768, kn);
      STAGEH(Bsrc, 1, nbase + 49152, kn);
    }

    // ---- 4 k-step phases, no interior barriers ----
#pragma unroll
    for (int ks = 0; ks < 4; ++ks) {
      const int qoff = (((ks << 1) + kg) ^ l7) << 4;   // swizzled 16B quad
#pragma unroll
      for (int mf = 0; mf < 4; ++mf)
        a[mf] = *(const bf16x8*)(Ab + arow + mf * 4096 + qoff);
#pragma unroll
      for (int nf = 0; nf < 2; ++nf)
        b[nf] = *(const bf16x8*)(Bb + brow + nf * 4096 + qoff);
      WAITLGKM0();
      SCHED0();
      __builtin_amdgcn_s_setprio(1);
#pragma unroll
      for (int mf = 0; mf < 4; ++mf)
#pragma unroll
        for (int nf = 0; nf < 2; ++nf)
          acc[mf][nf] = __builtin_amdgcn_mfma_f32_32x32x16_bf16(
              a[mf], b[nf], acc[mf][nf], 0, 0, 0);
      __builtin_amdgcn_s_setprio(0);
      SCHED0();
    }

    WAITVM0();     // stages issued at tile start -> effectively free
    BARRIER();     // the only block-wide sync per tile
  }
#undef STAGEH

  // ---- epilogue: C/D col = lane&31, row = (reg&3)+8*(reg>>2)+4*(lane>>5) ----
#pragma unroll
  for (int nf = 0; nf < 2; ++nf) {
    const int col = bn0 + wn + nf * 32 + l31;
    const float bv = bias[col];
#pragma unroll
    for (int mf = 0; mf < 4; ++mf) {
      const int rbase = bm0 + wm + mf * 32 + 4 * kg;
#pragma unroll
      for (int r = 0; r < 16; ++r) {
        const int row = rbase + (r & 3) + 8 * (r >> 2);
        C[(size_t)row * Mn + col] = acc[mf][nf][r] + bv;
      }
    }
  }
}

extern "C" void kernel_launch(void* const* d_in, const int* in_sizes, int n_in,
                              void* d_out, int out_size, void* d_ws, size_t ws_size,
                              hipStream_t stream) {
  const float* x     = (const float*)d_in[0];
  const float* dw    = (const float*)d_in[1];
  const float* bias  = (const float*)d_in[2];
  const float* sv    = (const float*)d_in[3];
  const int*   rows  = (const int*)d_in[4];
  const int*   cols  = (const int*)d_in[5];
  float* out = (float*)d_out;

  const int  Mn = in_sizes[2];                       // 4096
  const long wElems = (long)in_sizes[1];             // M*K
  const int  K  = (int)(wElems / Mn);                // 4096
  const long xElems = (long)in_sizes[0];             // T*K
  const int  Tm = (int)(xElems / K);                 // 8192
  const int  nnz = in_sizes[3];

  unsigned short* Wb = (unsigned short*)d_ws;        // [M*K] bf16
  unsigned short* Xb = Wb + wElems;                  // [T*K] bf16

  cvt_f32_bf16<<<2048, 256, 0, stream>>>(dw, Wb, wElems / 8);
  sparse_scatter<<<(nnz + 255) / 256, 256, 0, stream>>>(dw, sv, rows, cols, Wb, nnz, K);
  cvt_f32_bf16<<<2048, 256, 0, stream>>>(x, Xb, xElems / 8);

  dim3 grid((Tm >> 8) * (Mn >> 8));                  // 32*16 = 512
  gemm32<<<grid, 512, 131072, stream>>>(Xb, Wb, bias, out, Tm, Mn, K);
}

// Round 14
// 302.461 us; speedup vs baseline: 1.2664x; 1.0851x over previous
//
#include <hip/hip_runtime.h>

// SparseWeights: y = x @ (W_dense + scatter(sparse))^T + bias
// Round 14: r7 base (best, 260us GEMM) + m201's missing element: register
// fragment prefetch ONE PHASE AHEAD with counted lgkmcnt, so each phase's
// LDS latency is covered by the previous MFMA cluster. Quadrants
// Q00(a03xb01) Q01(a03xb23) Q10(a47xb01) Q11(a47xb23); reads lead by one
// phase; A-buffer shared between a03/a47 (reloaded after Q01's cluster)
// to stay at r7's 16-frag register budget (2 blocks/CU preserved).
// r13 lesson: 32x32 frags = 4-way bank alias; back to 16x16x32.

typedef __attribute__((ext_vector_type(8))) __bf16 bf16x8;
typedef __attribute__((ext_vector_type(4))) float f32x4;
typedef __attribute__((ext_vector_type(8))) unsigned short u16x8;

#define BARRIER()   asm volatile("s_barrier" ::: "memory")
#define WAITLGKM(n) asm volatile("s_waitcnt lgkmcnt(" #n ")" ::: "memory")
#define WAITVM0()   asm volatile("s_waitcnt vmcnt(0)" ::: "memory")
#define SCHED0()    __builtin_amdgcn_sched_barrier(0)

__device__ __forceinline__ unsigned short f2bf(float f) {
  unsigned int u = __builtin_bit_cast(unsigned int, f);
  u += 0x7FFFu + ((u >> 16) & 1u);   // round-to-nearest-even
  return (unsigned short)(u >> 16);
}

// ---- prepass 1/3: f32 -> bf16 bulk convert (vectorized x8) ----
__global__ __launch_bounds__(256) void cvt_f32_bf16(
    const float* __restrict__ s, unsigned short* __restrict__ d, long n8) {
  long i = (long)blockIdx.x * blockDim.x + threadIdx.x;
  const long stride = (long)gridDim.x * blockDim.x;
  for (; i < n8; i += stride) {
    const float4* sp = (const float4*)(s + i * 8);
    float4 a = sp[0];
    float4 b = sp[1];
    u16x8 o;
    o[0] = f2bf(a.x); o[1] = f2bf(a.y); o[2] = f2bf(a.z); o[3] = f2bf(a.w);
    o[4] = f2bf(b.x); o[5] = f2bf(b.y); o[6] = f2bf(b.z); o[7] = f2bf(b.w);
    *(u16x8*)(d + i * 8) = o;
  }
}

// ---- prepass 2/3: scatter sparse values into bf16 W ----
__global__ __launch_bounds__(256) void sparse_scatter(
    const float* __restrict__ dense, const float* __restrict__ vals,
    const int* __restrict__ rows, const int* __restrict__ cols,
    unsigned short* __restrict__ Wb, int nnz, int K) {
  int i = blockIdx.x * blockDim.x + threadIdx.x;
  if (i < nnz) {
    size_t off = (size_t)rows[i] * (size_t)K + (size_t)cols[i];
    Wb[off] = f2bf(dense[off] + vals[i]);
  }
}

// =====================================================================
// 256x256 GEMM, 512 threads = 8 waves (2Mx4N), wave tile 128x64 =
// acc[8][4] of 16x16x32 frags, BK=64 (kk=0,1). LDS 2 x (A 32K + B 32K)
// = 128 KiB dbuf. Rows 128 B = 8 quads; LDS quad q of row r holds global
// quad q^(r&7) (pre-swizzled source, swizzled read; 0 conflicts r6-r9).
//
// Lead-1 pipeline per tile t (buf = t&1):
//  X1 (end of prev iter): MFMA Q11(t-1); read a03(t)+b01(t) [12];
//     stage-all(t+2) [8 gl_lds]
//  X2: read b23(t) [4]; lgkm(4) {drains 12, keeps b23}; Q00 = a03xb01
//  X3: lgkm(0) {b23, covered by Q00}; Q01 = a03xb23; read a47(t) [8]
//     into SHARED A-buffer (after cluster: WAR-at-issue safe, SCHED0)
//  X4: lgkm(0) {a47, ~uncovered — the one stall/tile}; Q10 = a47xb01;
//     vmcnt(0) {stages(t+1), 3 phases old -> free}; BARRIER
// Ledger: buf(t+1) published by X4(t)'s vmcnt0+barrier before X1's reads
// of t+1. Stage(t+2) targets buf(t&1) whose last reads (a47(t)) drained
// at X4(t)'s lgkm(0) before the barrier. lgkm counts pinned by SCHED0
// after every read group.
// =====================================================================
__global__ __launch_bounds__(512, 2) void gemm14(
    const unsigned short* __restrict__ A,   // [Tm][K] bf16
    const unsigned short* __restrict__ B,   // [Mn][K] bf16
    const float* __restrict__ bias,
    float* __restrict__ C,
    int Tm, int Mn, int K) {
  extern __shared__ __align__(16) char smem[];   // 2 x 65536

  const int tid  = threadIdx.x;
  const int lane = tid & 63;
  const int wid  = tid >> 6;
  const int wm = (wid >> 2) * 128;
  const int wn = (wid & 3) * 64;

  // T1: XCD-aware bijective swizzle (nwg = 512, % 8 == 0)
  const int nwg = gridDim.x;
  int bid = blockIdx.x;
  if ((nwg & 7) == 0) bid = (bid & 7) * (nwg >> 3) + (bid >> 3);
  const int ntn = Mn >> 8;
  const int bm0 = (bid / ntn) << 8;
  const int bn0 = (bid % ntn) << 8;

  const int NT = K >> 6;             // K-tiles of 64

  // ---- staging (identical mapping to r6/r7, correctness-verified) ----
  const int sr  = tid >> 3;                          // 0..63
  const int gq8 = ((tid & 7) ^ (sr & 7)) * 8;        // pre-swizzled elem off
  const unsigned short* Asrc = A + (size_t)(bm0 + sr) * K + gq8;
  const unsigned short* Bsrc = B + (size_t)(bn0 + sr) * K + gq8;
  const size_t r64 = (size_t)64 * K;
  const int ldst = tid * 16;

#define STAGEH(SRC, H, LDSB, KOFF) do {                                          \
    __builtin_amdgcn_global_load_lds(                                            \
      (const __attribute__((address_space(1))) void*)((SRC) + (size_t)(H)*2*r64 + (KOFF)), \
      (__attribute__((address_space(3))) void*)(smem + (LDSB) + ldst), 16, 0, 0);\
    __builtin_amdgcn_global_load_lds(                                            \
      (const __attribute__((address_space(1))) void*)((SRC) + (size_t)(H)*2*r64 + r64 + (KOFF)), \
      (__attribute__((address_space(3))) void*)(smem + (LDSB) + 8192 + ldst), 16, 0, 0); \
  } while (0)

#define STAGEALL(NB, KO) do {                                                    \
    STAGEH(Asrc, 0, (NB), (KO));                                                 \
    STAGEH(Asrc, 1, (NB) + 16384, (KO));                                         \
    STAGEH(Bsrc, 0, (NB) + 32768, (KO));                                         \
    STAGEH(Bsrc, 1, (NB) + 49152, (KO));                                         \
  } while (0)

  // ---- read offsets: frag (row R, kk, cq) -> byte R*128 + ((kk*4+cq)^(R&7))*16
  const int fr = lane & 15, cq = lane >> 4;
  const int f7 = fr & 7;
  const int q0 = ((cq ^ f7) << 4);          // kk = 0
  const int q1 = (((4 + cq) ^ f7) << 4);    // kk = 1
  const int arow = (wm + fr) * 128;
  const int brow = (wn + fr) * 128;

  f32x4 acc[8][4] = {};
  bf16x8 Aq0[4], Aq1[4];                    // shared a03 / a47
  bf16x8 b1q0[2], b1q1[2], b2q0[2], b2q1[2];

#define READ12(BUF) do {                                                         \
    _Pragma("unroll")                                                            \
    for (int m = 0; m < 4; ++m) {                                                \
      Aq0[m] = *(const bf16x8*)((BUF) + arow + m * 2048 + q0);                   \
      Aq1[m] = *(const bf16x8*)((BUF) + arow + m * 2048 + q1);                   \
    }                                                                            \
    _Pragma("unroll")                                                            \
    for (int n = 0; n < 2; ++n) {                                                \
      b1q0[n] = *(const bf16x8*)((BUF) + 32768 + brow + n * 2048 + q0);          \
      b1q1[n] = *(const bf16x8*)((BUF) + 32768 + brow + n * 2048 + q1);          \
    }                                                                            \
  } while (0)

#define READB23(BUF) do {                                                        \
    _Pragma("unroll")                                                            \
    for (int n = 0; n < 2; ++n) {                                                \
      b2q0[n] = *(const bf16x8*)((BUF) + 32768 + brow + (n + 2) * 2048 + q0);    \
      b2q1[n] = *(const bf16x8*)((BUF) + 32768 + brow + (n + 2) * 2048 + q1);    \
    }                                                                            \
  } while (0)

#define READA47(BUF) do {                                                        \
    _Pragma("unroll")                                                            \
    for (int m = 0; m < 4; ++m) {                                                \
      Aq0[m] = *(const bf16x8*)((BUF) + arow + (m + 4) * 2048 + q0);             \
      Aq1[m] = *(const bf16x8*)((BUF) + arow + (m + 4) * 2048 + q1);             \
    }                                                                            \
  } while (0)

#define QUAD(MB, NB, BQ0, BQ1) do {                                              \
    __builtin_amdgcn_s_setprio(1);                                               \
    _Pragma("unroll")                                                            \
    for (int m = 0; m < 4; ++m)                                                  \
      _Pragma("unroll")                                                          \
      for (int n = 0; n < 2; ++n) {                                              \
        acc[m+(MB)][n+(NB)] = __builtin_amdgcn_mfma_f32_16x16x32_bf16(           \
            Aq0[m], BQ0[n], acc[m+(MB)][n+(NB)], 0, 0, 0);                       \
        acc[m+(MB)][n+(NB)] = __builtin_amdgcn_mfma_f32_16x16x32_bf16(           \
            Aq1[m], BQ1[n], acc[m+(MB)][n+(NB)], 0, 0, 0);                       \
      }                                                                          \
    __builtin_amdgcn_s_setprio(0);                                               \
  } while (0)

  // ---- prologue: stage tile 0; publish; lead-1 reads of tile 0; stage 1 ----
  STAGEALL(0, 0);
  WAITVM0();
  BARRIER();
  READ12(smem);
  SCHED0();
  if (NT > 1) STAGEALL(65536, 64);
  SCHED0();

  for (int t = 0; t < NT; ++t) {
    const char* buf = smem + (t & 1) * 65536;

    // ---- X2: b23 reads; counted lgkm(4); Q00 ----
    READB23(buf);
    SCHED0();
    WAITLGKM(4);          // drain a03+b01 (12); b23 (4) stays in flight
    SCHED0();
    QUAD(0, 0, b1q0, b1q1);
    SCHED0();

    // ---- X3: lgkm(0) (b23, covered by Q00); Q01; a47 reads after ----
    WAITLGKM(0);
    SCHED0();
    QUAD(0, 2, b2q0, b2q1);
    SCHED0();
    READA47(buf);         // overwrites shared A after Q01 latched a03
    SCHED0();

    // ---- X4: lgkm(0) (a47); Q10; drain stages; publish ----
    WAITLGKM(0);
    SCHED0();
    QUAD(4, 0, b1q0, b1q1);
    WAITVM0();            // stages(t+1): issued ~3 clusters ago -> free
    BARRIER();

    // ---- X1 of next frame: Q11; lead-1 reads(t+1); stage(t+2) ----
    QUAD(4, 2, b2q0, b2q1);
    SCHED0();
    if (t + 1 < NT) {
      const char* nbuf = smem + ((t + 1) & 1) * 65536;
      READ12(nbuf);       // overwrites A (a47 latched by Q11) + b01
      SCHED0();
      if (t + 2 < NT) STAGEALL((t & 1) * 65536, (t + 2) * 64);
      SCHED0();
    }
  }
#undef QUAD
#undef READA47
#undef READB23
#undef READ12
#undef STAGEALL
#undef STAGEH

  // ---- epilogue: C/D layout col = lane&15, row = (lane>>4)*4 + q ----
  const int c4 = cq * 4;
#pragma unroll
  for (int n = 0; n < 4; ++n) {
    const int col = bn0 + wn + n * 16 + fr;
    const float bv = bias[col];
#pragma unroll
    for (int m = 0; m < 8; ++m) {
      const size_t rowb = (size_t)(bm0 + wm + m * 16 + c4);
#pragma unroll
      for (int q = 0; q < 4; ++q)
        C[(rowb + q) * (size_t)Mn + col] = acc[m][n][q] + bv;
    }
  }
}

extern "C" void kernel_launch(void* const* d_in, const int* in_sizes, int n_in,
                              void* d_out, int out_size, void* d_ws, size_t ws_size,
                              hipStream_t stream) {
  const float* x     = (const float*)d_in[0];
  const float* dw    = (const float*)d_in[1];
  const float* bias  = (const float*)d_in[2];
  const float* sv    = (const float*)d_in[3];
  const int*   rows  = (const int*)d_in[4];
  const int*   cols  = (const int*)d_in[5];
  float* out = (float*)d_out;

  const int  Mn = in_sizes[2];                       // 4096
  const long wElems = (long)in_sizes[1];             // M*K
  const int  K  = (int)(wElems / Mn);                // 4096
  const long xElems = (long)in_sizes[0];             // T*K
  const int  Tm = (int)(xElems / K);                 // 8192
  const int  nnz = in_sizes[3];

  unsigned short* Wb = (unsigned short*)d_ws;        // [M*K] bf16
  unsigned short* Xb = Wb + wElems;                  // [T*K] bf16

  cvt_f32_bf16<<<2048, 256, 0, stream>>>(dw, Wb, wElems / 8);
  sparse_scatter<<<(nnz + 255) / 256, 256, 0, stream>>>(dw, sv, rows, cols, Wb, nnz, K);
  cvt_f32_bf16<<<2048, 256, 0, stream>>>(x, Xb, xElems / 8);

  dim3 grid((Tm >> 8) * (Mn >> 8));                  // 32*16 = 512
  gemm14<<<grid, 512, 131072, stream>>>(Xb, Wb, bias, out, Tm, Mn, K);
}